// Round 3
// baseline (82.648 us; speedup 1.0000x reference)
//
#include <hip/hip_runtime.h>
#include <hip/hip_bf16.h>
#include <hip/hip_cooperative_groups.h>

namespace cg = cooperative_groups;

// Closed-form reduction:
//   s = A @ x  (A: [5000,20], x: [20])
//   loss = sum_{i,j} (s_i - b_j)^2
//        = N * sum(s^2) - 2 * sum(s) * sum(b) + N * sum(b^2),  N = 5000
//
// Single cooperative dispatch: 20 blocks x 256 threads = 5120 threads, one
// row per thread (no loop). Per-block partials (wave shuffle + LDS) to d_ws,
// __threadfence + grid.sync, block 0 reduces the 20 quadruples and emits the
// scalar. Deterministic, no atomics, no d_out/d_ws init dependency.

#define N_ROWS 5000
#define N_FEAT 20
#define NBLK   20
#define BLKSZ  256
#define NWAVES (BLKSZ / 64)

__device__ __forceinline__ double wave_reduce_sum(double v) {
    #pragma unroll
    for (int off = 32; off > 0; off >>= 1)
        v += __shfl_down(v, off, 64);
    return v;
}

__global__ __launch_bounds__(BLKSZ) void lsq_coop_kernel(
        const float* __restrict__ A, const float* __restrict__ b,
        const float* __restrict__ x, double* __restrict__ ws,
        float* __restrict__ out) {
    __shared__ float xs[N_FEAT];
    if (threadIdx.x < N_FEAT) xs[threadIdx.x] = x[threadIdx.x];
    __syncthreads();

    double s1 = 0.0, s2 = 0.0, b1 = 0.0, b2 = 0.0;
    int i = blockIdx.x * BLKSZ + threadIdx.x;
    if (i < N_ROWS) {
        const float4* __restrict__ row = (const float4*)(A + (long)i * N_FEAT);
        float4 r0 = row[0], r1 = row[1], r2 = row[2], r3 = row[3], r4 = row[4];
        float bv = b[i];
        float s = r0.x * xs[0]  + r0.y * xs[1]  + r0.z * xs[2]  + r0.w * xs[3]
                + r1.x * xs[4]  + r1.y * xs[5]  + r1.z * xs[6]  + r1.w * xs[7]
                + r2.x * xs[8]  + r2.y * xs[9]  + r2.z * xs[10] + r2.w * xs[11]
                + r3.x * xs[12] + r3.y * xs[13] + r3.z * xs[14] + r3.w * xs[15]
                + r4.x * xs[16] + r4.y * xs[17] + r4.z * xs[18] + r4.w * xs[19];
        s1 = (double)s;
        s2 = (double)s * (double)s;
        b1 = (double)bv;
        b2 = (double)bv * (double)bv;
    }

    s1 = wave_reduce_sum(s1);
    s2 = wave_reduce_sum(s2);
    b1 = wave_reduce_sum(b1);
    b2 = wave_reduce_sum(b2);

    __shared__ double red[NWAVES][4];
    int lane = threadIdx.x & 63;
    int wave = threadIdx.x >> 6;
    if (lane == 0) {
        red[wave][0] = s1; red[wave][1] = s2;
        red[wave][2] = b1; red[wave][3] = b2;
    }
    __syncthreads();
    if (threadIdx.x == 0) {
        double t0 = 0, t1 = 0, t2 = 0, t3 = 0;
        #pragma unroll
        for (int w = 0; w < NWAVES; ++w) {
            t0 += red[w][0]; t1 += red[w][1];
            t2 += red[w][2]; t3 += red[w][3];
        }
        double* p = ws + 4 * blockIdx.x;
        p[0] = t0; p[1] = t1; p[2] = t2; p[3] = t3;
        __threadfence();   // device-scope release of ws before grid sync
    }

    cg::this_grid().sync();

    if (blockIdx.x == 0) {
        double v1 = 0, v2 = 0, v3 = 0, v4 = 0;
        if (threadIdx.x < NBLK) {
            volatile const double* p = ws + 4 * threadIdx.x;
            v1 = p[0]; v2 = p[1]; v3 = p[2]; v4 = p[3];
        }
        if (threadIdx.x < 64) {
            v1 = wave_reduce_sum(v1);
            v2 = wave_reduce_sum(v2);
            v3 = wave_reduce_sum(v3);
            v4 = wave_reduce_sum(v4);
            if (threadIdx.x == 0) {
                double n = (double)N_ROWS;
                out[0] = (float)(n * v2 - 2.0 * v1 * v3 + n * v4);
            }
        }
    }
}

extern "C" void kernel_launch(void* const* d_in, const int* in_sizes, int n_in,
                              void* d_out, int out_size, void* d_ws, size_t ws_size,
                              hipStream_t stream) {
    const float* A = (const float*)d_in[0];   // [5000,20]
    const float* b = (const float*)d_in[1];   // [5000]
    const float* x = (const float*)d_in[2];   // [20]
    double* ws = (double*)d_ws;               // 20 blocks * 4 doubles = 640 B
    float* out = (float*)d_out;

    void* args[] = {(void*)&A, (void*)&b, (void*)&x, (void*)&ws, (void*)&out};
    hipLaunchCooperativeKernel((void*)lsq_coop_kernel, dim3(NBLK), dim3(BLKSZ),
                               args, 0, stream);
}

// Round 4
// 58.811 us; speedup vs baseline: 1.4053x; 1.4053x over previous
//
#include <hip/hip_runtime.h>
#include <hip/hip_bf16.h>

// Closed-form reduction:
//   s = A @ x  (A: [5000,20], x: [20])
//   loss = sum_{i,j} (s_i - b_j)^2
//        = N * sum(s^2) - 2 * sum(s) * sum(b) + N * sum(b^2),  N = 5000
//
// R1 structure (best measured: 59.7 us): two plain dispatches.
//   K1: 20 blocks x 256 threads, one row/thread, float4 row loads,
//       per-block partials (S1,S2,B1,B2) via wave shuffle + LDS -> d_ws.
//   K2: one 64-thread block reduces the 20 quadruples, emits scalar.
// Cooperative launch (R3) regressed ~20 us; single-block (R2) ~3 us slower.
// Timed window is dominated by harness reset (256 MB ws poison = 40 us).

#define N_ROWS 5000
#define N_FEAT 20
#define NBLK   20
#define BLKSZ  256
#define NWAVES (BLKSZ / 64)

__device__ __forceinline__ double wave_reduce_sum(double v) {
    #pragma unroll
    for (int off = 32; off > 0; off >>= 1)
        v += __shfl_down(v, off, 64);
    return v;
}

__global__ __launch_bounds__(BLKSZ) void lsq_partial_kernel(
        const float* __restrict__ A, const float* __restrict__ b,
        const float* __restrict__ x, double* __restrict__ ws) {
    __shared__ float xs[N_FEAT];
    if (threadIdx.x < N_FEAT) xs[threadIdx.x] = x[threadIdx.x];
    __syncthreads();

    double s1 = 0.0, s2 = 0.0, b1 = 0.0, b2 = 0.0;
    int i = blockIdx.x * BLKSZ + threadIdx.x;   // 5120 threads >= 5000 rows
    if (i < N_ROWS) {
        const float4* __restrict__ row = (const float4*)(A + (long)i * N_FEAT);
        float4 r0 = row[0], r1 = row[1], r2 = row[2], r3 = row[3], r4 = row[4];
        float bv = b[i];
        float s = r0.x * xs[0]  + r0.y * xs[1]  + r0.z * xs[2]  + r0.w * xs[3]
                + r1.x * xs[4]  + r1.y * xs[5]  + r1.z * xs[6]  + r1.w * xs[7]
                + r2.x * xs[8]  + r2.y * xs[9]  + r2.z * xs[10] + r2.w * xs[11]
                + r3.x * xs[12] + r3.y * xs[13] + r3.z * xs[14] + r3.w * xs[15]
                + r4.x * xs[16] + r4.y * xs[17] + r4.z * xs[18] + r4.w * xs[19];
        s1 = (double)s;
        s2 = (double)s * (double)s;
        b1 = (double)bv;
        b2 = (double)bv * (double)bv;
    }

    s1 = wave_reduce_sum(s1);
    s2 = wave_reduce_sum(s2);
    b1 = wave_reduce_sum(b1);
    b2 = wave_reduce_sum(b2);

    __shared__ double red[NWAVES][4];
    int lane = threadIdx.x & 63;
    int wave = threadIdx.x >> 6;
    if (lane == 0) {
        red[wave][0] = s1; red[wave][1] = s2;
        red[wave][2] = b1; red[wave][3] = b2;
    }
    __syncthreads();
    if (threadIdx.x == 0) {
        double t0 = 0, t1 = 0, t2 = 0, t3 = 0;
        #pragma unroll
        for (int w = 0; w < NWAVES; ++w) {
            t0 += red[w][0]; t1 += red[w][1];
            t2 += red[w][2]; t3 += red[w][3];
        }
        double* p = ws + 4 * blockIdx.x;
        p[0] = t0; p[1] = t1; p[2] = t2; p[3] = t3;
    }
}

__global__ __launch_bounds__(64) void lsq_finalize_kernel(
        const double* __restrict__ ws, float* __restrict__ out) {
    double s1 = 0, s2 = 0, b1 = 0, b2 = 0;
    if (threadIdx.x < NBLK) {
        const double* p = ws + 4 * threadIdx.x;
        s1 = p[0]; s2 = p[1]; b1 = p[2]; b2 = p[3];
    }
    s1 = wave_reduce_sum(s1);
    s2 = wave_reduce_sum(s2);
    b1 = wave_reduce_sum(b1);
    b2 = wave_reduce_sum(b2);
    if (threadIdx.x == 0) {
        double n = (double)N_ROWS;
        out[0] = (float)(n * s2 - 2.0 * s1 * b1 + n * b2);
    }
}

extern "C" void kernel_launch(void* const* d_in, const int* in_sizes, int n_in,
                              void* d_out, int out_size, void* d_ws, size_t ws_size,
                              hipStream_t stream) {
    const float* A = (const float*)d_in[0];   // [5000,20]
    const float* b = (const float*)d_in[1];   // [5000]
    const float* x = (const float*)d_in[2];   // [20]
    float* out = (float*)d_out;
    double* ws = (double*)d_ws;               // 20 blocks * 4 doubles = 640 B

    lsq_partial_kernel<<<NBLK, BLKSZ, 0, stream>>>(A, b, x, ws);
    lsq_finalize_kernel<<<1, 64, 0, stream>>>(ws, out);
}